// Round 7
// baseline (79.266 us; speedup 1.0000x reference)
//
#include <hip/hip_runtime.h>

#define NB   4
#define KCH  4
#define P    4096          // 64*64 downsampled points per batch
#define QT   64            // q per block (as 32 packed pairs)
#define BLK  256           // threads per block
#define PT   2             // p per thread (p-tile = 512)
#define NPT  8             // p-tiles per batch
#define NBLK 288           // triangle blocks per batch: sum(64-8*pt)

#if __has_builtin(__builtin_amdgcn_exp2f)
#define EXPFN(x) __builtin_amdgcn_exp2f(x)
#define FSCALE 1.2011224087864498f   /* sqrt(log2(e)) */
#else
#define EXPFN(x) __expf(x)
#define FSCALE 1.0f
#endif

typedef float v2f __attribute__((ext_vector_type(2)));

// Bare canonical VOP3P packed fp32: d.lo = op(a.lo,b.lo[,c.lo]), d.hi = ...hi.
// No op_sel modifiers anywhere (Round-6 failure isolated those as unverified).
__device__ __forceinline__ v2f pk_fma(v2f a, v2f b, v2f c) {
    v2f d;
    asm("v_pk_fma_f32 %0, %1, %2, %3" : "=v"(d) : "v"(a), "v"(b), "v"(c));
    return d;
}
__device__ __forceinline__ v2f pk_add(v2f a, v2f b) {
    v2f d;
    asm("v_pk_add_f32 %0, %1, %2" : "=v"(d) : "v"(a), "v"(b));
    return d;
}
__device__ __forceinline__ v2f pk_mul(v2f a, v2f b) {
    v2f d;
    asm("v_pk_mul_f32 %0, %1, %2" : "=v"(d) : "v"(a), "v"(b));
    return d;
}

// Compute one downsampled-point record directly from raw inputs (R5-proven).
__device__ __forceinline__ void make_rec(const float* __restrict__ images,
                                         const float* __restrict__ segs,
                                         int n, int p, float* o /*[10]*/) {
    int i = p >> 6;
    int j = p & 63;
    int off = 256 * i + 2 * j;
    const float* img = images + (size_t)n * 3 * 16384;
    float x = (float)j * (FSCALE / 50.0f);     // SIGMA_XY*SCALE = 50
    float y = (float)i * (FSCALE / 50.0f);
    float r = img[0 * 16384 + off] * (FSCALE / 15.0f);   // SIGMA_RGB = 15
    float g = img[1 * 16384 + off] * (FSCALE / 15.0f);
    float b = img[2 * 16384 + off] * (FSCALE / 15.0f);
    float h = -0.5f * (x * x + y * y + r * r + g * g + b * b);
    o[0] = x; o[1] = y; o[2] = r; o[3] = g; o[4] = b; o[5] = h;
    const float* sg = segs + (size_t)n * KCH * 16384;
#pragma unroll
    for (int k = 0; k < KCH; ++k) {
        float2 s0 = *(const float2*)(sg + k * 16384 + off);
        float2 s1 = *(const float2*)(sg + k * 16384 + off + 128);
        o[6 + k] = 0.25f * ((s0.x + s0.y) + (s1.x + s1.y));
    }
}

// Fused kernel: inline prep + packed-fp32 symmetric pairwise reduction.
// LDS holds 32 q-PAIRS interleaved: qlds[pair][i] = {feat_i(q0), feat_i(q1)},
// so all inner math is plain packed (p-features splatted in registers).
// grid = (288 triangle blocks, 4 batches).
__global__ __launch_bounds__(256) void crf_fused(const float* __restrict__ images,
                                                 const float* __restrict__ segs,
                                                 float* __restrict__ out) {
    __shared__ v2f qlds[(QT / 2) * 10];   // 32 pairs x 10 features = 2.5 KB
    __shared__ float wsum[BLK / 64];

    int t = threadIdx.x;
    int n = blockIdx.y;

    // Decode triangle block index -> (p-tile pt, q-chunk qc), qc >= 8*pt.
    static const int cum[NPT] = {0, 64, 120, 168, 208, 240, 264, 280};
    int b = blockIdx.x;
    int pt = 0;
#pragma unroll
    for (int i = 1; i < NPT; ++i) pt += (b >= cum[i]) ? 1 : 0;
    int qc = b - cum[pt] + 8 * pt;
    int pbase = pt * (BLK * PT);
    int qbase = qc * QT;
    bool mixed = (qc >> 3) == pt;

    // q-records: first QT threads build one record each, write interleaved.
    if (t < QT) {
        float o[10];
        make_rec(images, segs, n, qbase + t, o);
        float* dst = (float*)qlds + (t >> 1) * 20 + (t & 1);
#pragma unroll
        for (int i = 0; i < 10; ++i) dst[2 * i] = o[i];
    }

    // p-records: PT=2 own records, each feature SPLATTED into both v2f halves.
    float a0[10], a1[10];
    make_rec(images, segs, n, pbase + t, a0);
    make_rec(images, segs, n, pbase + t + BLK, a1);
    v2f rp0[10], rp1[10];
#pragma unroll
    for (int i = 0; i < 10; ++i) {
        rp0[i] = (v2f){a0[i], a0[i]};
        rp1[i] = (v2f){a1[i], a1[i]};
    }
    __syncthreads();

    v2f acc0 = (v2f){0.f, 0.f}, acc1 = (v2f){0.f, 0.f};
    float acc_all;

    if (!mixed) {
        // Strictly above the diagonal: every pair counts twice.
#pragma unroll 4
        for (int qq = 0; qq < QT / 2; ++qq) {
            const v2f* l = qlds + qq * 10;     // wave-uniform -> LDS broadcast
            v2f l0 = l[0], l1 = l[1], l2 = l[2], l3 = l[3], l4 = l[4];
            v2f l5 = l[5], l6 = l[6], l7 = l[7], l8 = l[8], l9 = l[9];
            {
                v2f d = pk_add(rp0[5], l5);            // h_p + h_q
                d = pk_fma(rp0[0], l0, d);
                d = pk_fma(rp0[1], l1, d);
                d = pk_fma(rp0[2], l2, d);
                d = pk_fma(rp0[3], l3, d);
                d = pk_fma(rp0[4], l4, d);
                v2f w; w.x = EXPFN(d.x); w.y = EXPFN(d.y);
                v2f sd = pk_mul(rp0[6], l6);
                sd = pk_fma(rp0[7], l7, sd);
                sd = pk_fma(rp0[8], l8, sd);
                sd = pk_fma(rp0[9], l9, sd);
                acc0 = pk_fma(w, sd, acc0);
            }
            {
                v2f d = pk_add(rp1[5], l5);
                d = pk_fma(rp1[0], l0, d);
                d = pk_fma(rp1[1], l1, d);
                d = pk_fma(rp1[2], l2, d);
                d = pk_fma(rp1[3], l3, d);
                d = pk_fma(rp1[4], l4, d);
                v2f w; w.x = EXPFN(d.x); w.y = EXPFN(d.y);
                v2f sd = pk_mul(rp1[6], l6);
                sd = pk_fma(rp1[7], l7, sd);
                sd = pk_fma(rp1[8], l8, sd);
                sd = pk_fma(rp1[9], l9, sd);
                acc1 = pk_fma(w, sd, acc1);
            }
        }
        acc_all = 2.0f * ((acc0.x + acc0.y) + (acc1.x + acc1.y));
    } else {
        // Diagonal-overlap block: weight pairs 2/1/0 for q>p / q==p / q<p.
        int pg0 = pbase + t;
        int pg1 = pbase + t + BLK;
#pragma unroll 2
        for (int qq = 0; qq < QT / 2; ++qq) {
            const v2f* l = qlds + qq * 10;
            v2f l0 = l[0], l1 = l[1], l2 = l[2], l3 = l[3], l4 = l[4];
            v2f l5 = l[5], l6 = l[6], l7 = l[7], l8 = l[8], l9 = l[9];
            int qg0 = qbase + 2 * qq;
            int qg1 = qg0 + 1;
            {
                v2f d = pk_add(rp0[5], l5);
                d = pk_fma(rp0[0], l0, d);
                d = pk_fma(rp0[1], l1, d);
                d = pk_fma(rp0[2], l2, d);
                d = pk_fma(rp0[3], l3, d);
                d = pk_fma(rp0[4], l4, d);
                v2f w; w.x = EXPFN(d.x); w.y = EXPFN(d.y);
                v2f sd = pk_mul(rp0[6], l6);
                sd = pk_fma(rp0[7], l7, sd);
                sd = pk_fma(rp0[8], l8, sd);
                sd = pk_fma(rp0[9], l9, sd);
                float flo = (qg0 > pg0) ? 2.0f : ((qg0 == pg0) ? 1.0f : 0.0f);
                float fhi = (qg1 > pg0) ? 2.0f : ((qg1 == pg0) ? 1.0f : 0.0f);
                acc0.x = fmaf(w.x, sd.x * flo, acc0.x);
                acc0.y = fmaf(w.y, sd.y * fhi, acc0.y);
            }
            {
                v2f d = pk_add(rp1[5], l5);
                d = pk_fma(rp1[0], l0, d);
                d = pk_fma(rp1[1], l1, d);
                d = pk_fma(rp1[2], l2, d);
                d = pk_fma(rp1[3], l3, d);
                d = pk_fma(rp1[4], l4, d);
                v2f w; w.x = EXPFN(d.x); w.y = EXPFN(d.y);
                v2f sd = pk_mul(rp1[6], l6);
                sd = pk_fma(rp1[7], l7, sd);
                sd = pk_fma(rp1[8], l8, sd);
                sd = pk_fma(rp1[9], l9, sd);
                float flo = (qg0 > pg1) ? 2.0f : ((qg0 == pg1) ? 1.0f : 0.0f);
                float fhi = (qg1 > pg1) ? 2.0f : ((qg1 == pg1) ? 1.0f : 0.0f);
                acc1.x = fmaf(w.x, sd.x * flo, acc1.x);
                acc1.y = fmaf(w.y, sd.y * fhi, acc1.y);
            }
        }
        acc_all = (acc0.x + acc0.y) + (acc1.x + acc1.y);
    }

#pragma unroll
    for (int off = 32; off > 0; off >>= 1)
        acc_all += __shfl_down(acc_all, off, 64);
    if ((t & 63) == 0) wsum[t >> 6] = acc_all;
    __syncthreads();
    if (t == 0) {
        float s = (wsum[0] + wsum[1]) + (wsum[2] + wsum[3]);
        // loss = WEIGHT * (-sum / n) = -1e-7/4 * sum
        atomicAdd(out, s * (-2.5e-8f));
    }
}

extern "C" void kernel_launch(void* const* d_in, const int* in_sizes, int n_in,
                              void* d_out, int out_size, void* d_ws, size_t ws_size,
                              hipStream_t stream) {
    const float* images = (const float*)d_in[0];
    const float* segs   = (const float*)d_in[1];
    float* out = (float*)d_out;
    (void)d_ws; (void)ws_size;

    (void)hipMemsetAsync(out, 0, sizeof(float), stream);
    crf_fused<<<dim3(NBLK, NB), dim3(256), 0, stream>>>(images, segs, out);
}